// Round 13
// baseline (132.855 us; speedup 1.0000x reference)
//
#include <hip/hip_runtime.h>
#include <hip/hip_bf16.h>
#include <stdint.h>

#define N_TOTAL 8192
#define HALF_N  4096
#define DIM     512
#define INV_TAU (1.0f/0.07f)

typedef __attribute__((ext_vector_type(4))) int   i32x4;

__device__ __forceinline__ uint32_t umax32(uint32_t a, uint32_t b) { return a > b ? a : b; }
__device__ __forceinline__ uint32_t umin32(uint32_t a, uint32_t b) { return a < b ? a : b; }

__device__ __forceinline__ float decode_key(uint32_t key)
{
    ushort h = (key & 0x8000u) ? (ushort)(key ^ 0x8000u) : (ushort)(key ^ 0xFFFFu);
    return (float)(*(_Float16*)&h);
}

// ------- Kernel 0: normalize -> int8 quantize (q=rint(127*z~)), inv_qn,
//         and zero rowsum (no separate memset) -------------------------
__global__ __launch_bounds__(256) void norm_kernel(const float* __restrict__ z1,
                                                   const float* __restrict__ z2,
                                                   char* __restrict__ zq,
                                                   float* __restrict__ inv_qn,
                                                   float* __restrict__ rowsum)
{
    if (threadIdx.x < 4) rowsum[blockIdx.x * 4 + threadIdx.x] = 0.f;

    int row  = blockIdx.x * 4 + (threadIdx.x >> 6);
    int lane = threadIdx.x & 63;
    const float* src = (row < HALF_N) ? (z1 + (size_t)row * DIM)
                                      : (z2 + (size_t)(row - HALF_N) * DIM);
    const float4* p = (const float4*)src;
    float4 a = p[lane * 2];
    float4 b = p[lane * 2 + 1];
    float ss = a.x*a.x + a.y*a.y + a.z*a.z + a.w*a.w
             + b.x*b.x + b.y*b.y + b.z*b.z + b.w*b.w;
#pragma unroll
    for (int o = 1; o < 64; o <<= 1) ss += __shfl_xor(ss, o);
    float sc = 127.0f / fmaxf(sqrtf(ss), 1e-12f);

    float v[8] = {a.x*sc, a.y*sc, a.z*sc, a.w*sc, b.x*sc, b.y*sc, b.z*sc, b.w*sc};
    char c8[8];
    int qq = 0;
#pragma unroll
    for (int j = 0; j < 8; j++) {
        int qi = (int)rintf(v[j]);
        qq += qi * qi;
        c8[j] = (char)qi;
    }
#pragma unroll
    for (int o = 1; o < 64; o <<= 1) qq += __shfl_xor(qq, o);
    if (lane == 0) inv_qn[row] = 1.0f / sqrtf(fmaxf((float)qq, 1.0f));

    *(uint2*)(zq + (size_t)row * DIM + lane * 8) = *(const uint2*)c8;
}

// ------- Kernel 1: upper-triangle 128x128 int8 MFMA GEMM, NO LDS ------
// zq is 4 MB -> fully L2-resident (R12: FETCH 14.5 MB vs 532 MB logical,
// 97% cache-hit). So skip LDS staging entirely (Common-mistake #7):
// each lane loads its MFMA fragments direct global->VGPR from 8 base
// pointers + kt*64 immediate offsets. No barriers, no LDS, no staging
// VALU; full unroll lets the compiler software-pipeline with its own
// vmcnt tracking. Epilogue identical to R12 (verified absmax 0.0).
__global__ __launch_bounds__(256, 4) void gemm_kernel(const char* __restrict__ zq,
                                                      const float* __restrict__ inv_qn,
                                                      float* __restrict__ rowsum,
                                                      uint2* __restrict__ partial,
                                                      float* __restrict__ pos_sim)
{
    // XCD-aware swizzle: 2080 = 8 * 260, bijective
    int orig = blockIdx.x;
    int bid  = (orig & 7) * 260 + (orig >> 3);

    // triangular decode: bid -> (by, bx), bx >= by, 64-wide upper triangle
    int by = (int)(64.5f - sqrtf(4160.25f - 2.0f * (float)bid));
    int off = 64 * by - (by * (by - 1)) / 2;
    if (off > bid) { --by; off = 64 * by - (by * (by - 1)) / 2; }
    else {
        int offn = 64 * (by + 1) - ((by + 1) * by) / 2;
        if (offn <= bid) { ++by; off = offn; }
    }
    int bx = by + (bid - off);

    const int brow = by * 128;
    const int bcol = bx * 128;

    const int t    = threadIdx.x;
    const int w    = t >> 6;
    const int lane = t & 63;
    const int wr   = w >> 1, wc = w & 1;       // 2x2 waves of 64x64

    i32x4 acc[4][4] = {};

    // per-lane fragment base pointers (fragment: row = base+(lane&15),
    // 16B K-chunk = lane>>4; per K-step offset = kt*64 bytes, imm-foldable)
    const char* pa[4];
    const char* pb[4];
#pragma unroll
    for (int m = 0; m < 4; m++) {
        pa[m] = zq + (size_t)(brow + wr * 64 + m * 16 + (lane & 15)) * DIM + (lane >> 4) * 16;
        pb[m] = zq + (size_t)(bcol + wc * 64 + m * 16 + (lane & 15)) * DIM + (lane >> 4) * 16;
    }

#pragma unroll
    for (int kt = 0; kt < DIM / 64; ++kt) {
        i32x4 av[4], bv[4];
#pragma unroll
        for (int m = 0; m < 4; m++) av[m] = *(const i32x4*)(pa[m] + kt * 64);
#pragma unroll
        for (int n = 0; n < 4; n++) bv[n] = *(const i32x4*)(pb[n] + kt * 64);
#pragma unroll
        for (int m = 0; m < 4; m++)
#pragma unroll
            for (int n = 0; n < 4; n++)
                acc[m][n] = __builtin_amdgcn_mfma_i32_16x16x64_i8(av[m], bv[n], acc[m][n], 0, 0, 0);
    }

    const bool is_cross = (brow < HALF_N) && (bcol >= HALF_N);
    const bool off_diag = (bx != by);

    float invc[4];
#pragma unroll
    for (int n = 0; n < 4; n++)
        invc[n] = inv_qn[bcol + wc * 64 + n * 16 + (lane & 15)];

    float    cs[4] = {0.f, 0.f, 0.f, 0.f};          // col-side exp sums
    uint32_t s1[4] = {0u, 0u, 0u, 0u};              // col-side top-2
    uint32_t s2[4] = {0u, 0u, 0u, 0u};

    // ---- single fused epilogue pass ----
#pragma unroll
    for (int m = 0; m < 4; m++) {
#pragma unroll
        for (int r = 0; r < 4; r++) {
            int grow = brow + wr * 64 + m * 16 + ((lane >> 4) << 2) + r;
            float invr = inv_qn[grow];
            float rs = 0.f;
            uint32_t t1 = 0u, t2 = 0u;
#pragma unroll
            for (int n = 0; n < 4; n++) {
                int gcol = bcol + wc * 64 + n * 16 + (lane & 15);
                float v  = (float)acc[m][n][r] * (invr * invc[n]);
                float e  = (grow == gcol) ? 0.f : __expf(v * INV_TAU);
                rs += e;
                cs[n] += e;
                if (is_cross) {
                    int cidx = gcol - HALF_N;
                    ushort h;
                    *(_Float16*)&h = (_Float16)v;
                    uint32_t key = ((uint32_t)(ushort)(h ^ (ushort)((ushort)((short)h >> 15) | 0x8000))) << 16;
                    uint32_t xr = key | (uint32_t)(4095 - cidx);   // row-side: col index
                    uint32_t mn = umin32(t1, xr);
                    t1 = umax32(t1, xr);
                    t2 = umax32(t2, mn);
                    uint32_t xc = key | (uint32_t)(4095 - grow);   // col-side: row index
                    mn = umin32(s1[n], xc);
                    s1[n] = umax32(s1[n], xc);
                    s2[n] = umax32(s2[n], mn);
                    if (cidx == grow) { pos_sim[grow] = v; pos_sim[gcol] = v; }
                }
            }
            rs += __shfl_xor(rs, 1);
            rs += __shfl_xor(rs, 2);
            rs += __shfl_xor(rs, 4);
            rs += __shfl_xor(rs, 8);
            if ((lane & 15) == 0) atomicAdd(&rowsum[grow], rs);

            if (is_cross) {
#pragma unroll
                for (int o = 1; o < 16; o <<= 1) {
                    uint32_t o1 = __shfl_xor(t1, o);
                    uint32_t o2 = __shfl_xor(t2, o);
                    uint32_t nt2 = umax32(umin32(t1, o1), umax32(t2, o2));
                    t1 = umax32(t1, o1);
                    t2 = nt2;
                }
                if ((lane & 15) == 0)
                    partial[((size_t)grow << 6) + (bx - 32) * 2 + wc] = make_uint2(t1, t2);
            }
        }
    }

    // ---- col-side finalize (reduce over lane bits 4,5 = row groups) ----
    if (off_diag) {
#pragma unroll
        for (int n = 0; n < 4; n++) {
            float c = cs[n];
            c += __shfl_xor(c, 16);
            c += __shfl_xor(c, 32);
            uint32_t a1 = s1[n], a2 = s2[n];
            if (is_cross) {
#pragma unroll
                for (int o = 16; o < 64; o <<= 1) {
                    uint32_t o1 = __shfl_xor(a1, o);
                    uint32_t o2 = __shfl_xor(a2, o);
                    uint32_t nt2 = umax32(umin32(a1, o1), umax32(a2, o2));
                    a1 = umax32(a1, o1);
                    a2 = nt2;
                }
            }
            if (lane < 16) {
                int gcol = bcol + wc * 64 + n * 16 + lane;
                atomicAdd(&rowsum[gcol], c);
                if (is_cross)
                    partial[((size_t)gcol << 6) + by * 2 + wr] = make_uint2(a1, a2);
            }
        }
    }
}

// ------- Kernel 2: per-row top-10 + per-row loss (64 full slots) -------
__global__ __launch_bounds__(256) void topk_loss_kernel(const uint2* __restrict__ partial,
                                                        const float* __restrict__ pos_sim,
                                                        const float* __restrict__ rowsum,
                                                        float* __restrict__ contrib)
{
    int i    = blockIdx.x * 4 + (threadIdx.x >> 6);
    int lane = threadIdx.x & 63;

    uint2 p = partial[((size_t)i << 6) + lane];
    uint32_t t1 = p.x, t2 = p.y;

    int posidx = i & (HALF_N - 1);
    float S10 = 0.f; int posflag = 0;
#pragma unroll
    for (int tc = 0; tc < 10; tc++) {
        uint32_t b = umax32(t1, t2);
#pragma unroll
        for (int o = 32; o; o >>= 1)
            b = umax32(b, __shfl_xor(b, o));
        bool w1 = (b == t1);
        bool w2 = (b == t2);
        t1 = w1 ? t2 : t1;
        t2 = (w1 | w2) ? 0u : t2;

        int idx = 4095 - (int)(b & 0xFFFFu);
        S10 += decode_key(b >> 16);
        posflag |= (idx == posidx) ? 1 : 0;
    }

    if (lane == 0) {
        float ps  = pos_sim[i];
        float lse = logf(rowsum[i]);
        float L   = 1.0f + 0.75f * (10 - posflag);
        float sll = INV_TAU * (ps + 0.75f * (S10 - posflag * ps));
        contrib[i] = L * lse - sll;
    }
}

// ------- Kernel 3: deterministic final reduce --------------------------
__global__ __launch_bounds__(256) void reduce_kernel(const float* __restrict__ contrib,
                                                     float* __restrict__ out)
{
    int t = threadIdx.x;
    float s = 0.f;
    for (int j = t; j < N_TOTAL; j += 256) s += contrib[j];
#pragma unroll
    for (int o = 1; o < 64; o <<= 1) s += __shfl_xor(s, o);
    __shared__ float wsum[4];
    if ((t & 63) == 0) wsum[t >> 6] = s;
    __syncthreads();
    if (t == 0) out[0] = (wsum[0] + wsum[1] + wsum[2] + wsum[3]) * (1.0f / N_TOTAL);
}

extern "C" void kernel_launch(void* const* d_in, const int* in_sizes, int n_in,
                              void* d_out, int out_size, void* d_ws, size_t ws_size,
                              hipStream_t stream)
{
    const float* z1 = (const float*)d_in[0];
    const float* z2 = (const float*)d_in[1];
    float* out = (float*)d_out;

    char* ws = (char*)d_ws;
    char*   zq      = ws;                              //  4 MB   8192x512 int8
    float*  rowsum  = (float*)(ws + 4194304);          // 32 KB
    float*  pos_sim = (float*)(ws + 4227072);          // 32 KB
    float*  inv_qn  = (float*)(ws + 4259840);          // 32 KB
    uint2*  partial = (uint2*)(ws + 4292608);          //  4 MB   8192x64 uint2
    float*  contrib = (float*)(ws + 8486912);          // 32 KB

    norm_kernel<<<N_TOTAL / 4, 256, 0, stream>>>(z1, z2, zq, inv_qn, rowsum);
    gemm_kernel<<<2080, 256, 0, stream>>>(zq, inv_qn, rowsum, partial, pos_sim);
    topk_loss_kernel<<<N_TOTAL / 4, 256, 0, stream>>>(partial, pos_sim, rowsum, contrib);
    reduce_kernel<<<1, 256, 0, stream>>>(contrib, out);
}